// Round 1
// baseline (5510.144 us; speedup 1.0000x reference)
//
#include <hip/hip_runtime.h>

#define HLAT 181
#define WLON 360
#define HW (HLAT * WLON)

// ---------------- kernel 0: weight transpose ----------------
// w2t[c*25+ij][64], w3t[c*25+ij][4] (o=3 padded with 0)
__global__ __launch_bounds__(256) void k_tw(const float* __restrict__ w2,
                                            const float* __restrict__ w3,
                                            float* __restrict__ w2t,
                                            float* __restrict__ w3t) {
  int idx = blockIdx.x * 256 + threadIdx.x;
  if (idx < 3200 * 64) {
    int ck = idx >> 6, o = idx & 63;
    int c = ck / 25, ij = ck % 25;
    w2t[idx] = w2[(o * 128 + c) * 25 + ij];
  }
  if (idx < 1600 * 4) {
    int ck = idx >> 2, o = idx & 3;
    int c = ck / 25, ij = ck % 25;
    w3t[idx] = (o < 3) ? w3[(o * 64 + c) * 25 + ij] : 0.f;
  }
}

// ---------------- kernel 1: disco conv (z on the fly) + w1 GEMM + relu ----
// grid (HLAT, bc), block 192. Each thread handles pixels w=tid and w=tid+180.
__global__ __launch_bounds__(192) void k_l1(const float* __restrict__ x,
    const float* __restrict__ psi, const float* __restrict__ quad,
    const float* __restrict__ w1, const float* __restrict__ b1,
    float* __restrict__ h1, int b0) {
  const int h = blockIdx.x;
  const int bi = blockIdx.y;
  const int b = b0 + bi;
  __shared__ __align__(16) float s_w1[128][28]; // [o][c*9+k], col27 = 0
  __shared__ float s_psi[9][25];
  __shared__ float s_b1[128];
  const int tid = threadIdx.x;
  for (int idx = tid; idx < 128 * 27; idx += 192) s_w1[idx / 27][idx % 27] = w1[idx];
  for (int idx = tid; idx < 225; idx += 192)
    s_psi[idx / 25][idx % 25] = psi[(idx / 25) * (HLAT * 25) + h * 25 + (idx % 25)];
  if (tid < 128) { s_w1[tid][27] = 0.f; s_b1[tid] = b1[tid]; }
  __syncthreads();
  if (tid >= 180) return;

  float z[2][28];
#pragma unroll
  for (int q = 0; q < 28; ++q) { z[0][q] = 0.f; z[1][q] = 0.f; }

#pragma unroll
  for (int c = 0; c < 3; ++c) {
#pragma unroll
    for (int i = 0; i < 5; ++i) {
      int hi = h + i - 2;
      hi = hi < 0 ? 0 : (hi >= HLAT ? HLAT - 1 : hi);
      const float qv = quad[hi];
      const float* row = x + ((size_t)(b * 3 + c) * HLAT + hi) * WLON;
      float v0[5], v1[5];
#pragma unroll
      for (int j = 0; j < 5; ++j) {
        int wj0 = tid + j - 2; wj0 = wj0 < 0 ? wj0 + WLON : wj0;
        int wj1 = tid + 180 + j - 2; wj1 = wj1 >= WLON ? wj1 - WLON : wj1;
        v0[j] = row[wj0] * qv;
        v1[j] = row[wj1] * qv;
      }
#pragma unroll
      for (int k = 0; k < 9; ++k) {
        float a0 = 0.f, a1 = 0.f;
#pragma unroll
        for (int j = 0; j < 5; ++j) {
          const float p = s_psi[k][i * 5 + j];
          a0 += p * v0[j];
          a1 += p * v1[j];
        }
        z[0][c * 9 + k] += a0;
        z[1][c * 9 + k] += a1;
      }
    }
  }
  z[0][27] = 0.f; z[1][27] = 0.f;

  float* op0 = h1 + (size_t)bi * 128 * HW + (size_t)h * WLON;
  for (int o = 0; o < 128; ++o) {
    float a0 = s_b1[o], a1 = a0;
#pragma unroll
    for (int q4 = 0; q4 < 7; ++q4) {
      const float4 wv = *(const float4*)&s_w1[o][q4 * 4];
      a0 += wv.x * z[0][q4 * 4 + 0] + wv.y * z[0][q4 * 4 + 1] +
            wv.z * z[0][q4 * 4 + 2] + wv.w * z[0][q4 * 4 + 3];
      a1 += wv.x * z[1][q4 * 4 + 0] + wv.y * z[1][q4 * 4 + 1] +
            wv.z * z[1][q4 * 4 + 2] + wv.w * z[1][q4 * 4 + 3];
    }
    float* op = op0 + (size_t)o * HW;
    op[tid] = fmaxf(a0, 0.f);
    op[tid + 180] = fmaxf(a1, 0.f);
  }
}

// ---------------- kernel 2: conv 128->64, 5x5, zero pad, relu -------------
// grid (12, 46, bc), block 256. Output tile 64oc x 4row x 32col.
// Thread: og=tid>>5 (8 ocs at og*8), pg=tid&31 -> ry=pg>>3, cx0=(pg&7)*4.
__global__ __launch_bounds__(256) void k_conv2(const float* __restrict__ h1,
    const float* __restrict__ w2t, const float* __restrict__ b2,
    float* __restrict__ h2) {
  const int x0 = blockIdx.x * 32;
  const int y0 = blockIdx.y * 4;
  const int bi = blockIdx.z;
  __shared__ __align__(16) float s_w[200][64];   // [ci*25+ij][oc]
  __shared__ __align__(16) float s_in[8][8][40]; // [ci][row][col] (36 used)
  const int tid = threadIdx.x;
  const int og = tid >> 5;
  const int pg = tid & 31;
  const int ry = pg >> 3;
  const int cx0 = (pg & 7) << 2;

  float acc[8][4];
#pragma unroll
  for (int a = 0; a < 8; ++a)
#pragma unroll
    for (int p = 0; p < 4; ++p) acc[a][p] = 0.f;

  for (int cc = 0; cc < 16; ++cc) {
    __syncthreads();
    const float4* wsrc = (const float4*)(w2t + (size_t)cc * 12800);
    for (int idx = tid; idx < 3200; idx += 256) ((float4*)s_w)[idx] = wsrc[idx];
    for (int idx = tid; idx < 8 * 8 * 36; idx += 256) {
      const int ci = idx / (8 * 36);
      const int r = (idx / 36) & 7;
      const int col = idx % 36;
      const int yy = y0 + r - 2;
      const int xx = x0 + col - 2;
      float v = 0.f;
      if (yy >= 0 && yy < HLAT && xx >= 0 && xx < WLON)
        v = h1[((size_t)(bi * 128 + cc * 8 + ci) * HLAT + yy) * WLON + xx];
      s_in[ci][r][col] = v;
    }
    __syncthreads();
    for (int ci = 0; ci < 8; ++ci) {
#pragma unroll
      for (int i = 0; i < 5; ++i) {
        const float4 a4 = *(const float4*)&s_in[ci][ry + i][cx0];
        const float4 b4 = *(const float4*)&s_in[ci][ry + i][cx0 + 4];
        const float win[8] = {a4.x, a4.y, a4.z, a4.w, b4.x, b4.y, b4.z, b4.w};
#pragma unroll
        for (int j = 0; j < 5; ++j) {
          const float4 wa = *(const float4*)&s_w[ci * 25 + i * 5 + j][og * 8];
          const float4 wb = *(const float4*)&s_w[ci * 25 + i * 5 + j][og * 8 + 4];
          const float wv[8] = {wa.x, wa.y, wa.z, wa.w, wb.x, wb.y, wb.z, wb.w};
#pragma unroll
          for (int p = 0; p < 4; ++p) {
            const float v = win[j + p];
#pragma unroll
            for (int oo = 0; oo < 8; ++oo) acc[oo][p] += wv[oo] * v;
          }
        }
      }
    }
  }
  const int oy = y0 + ry;
  if (oy < HLAT) {
#pragma unroll
    for (int oo = 0; oo < 8; ++oo) {
      const int o = og * 8 + oo;
      const float bb = b2[o];
      float* dst = h2 + ((size_t)(bi * 64 + o) * HLAT + oy) * WLON;
#pragma unroll
      for (int p = 0; p < 4; ++p) {
        const int ox = x0 + cx0 + p;
        if (ox < WLON) dst[ox] = fmaxf(acc[oo][p] + bb, 0.f);
      }
    }
  }
}

// ---------------- kernel 3: conv 64->3, 5x5, zero pad ---------------------
// grid (3, 23, bc), block 256. Tile 3oc x 8row x 128col; thread = 4 px.
__global__ __launch_bounds__(256) void k_conv3(const float* __restrict__ h2,
    const float* __restrict__ w3t, const float* __restrict__ b3,
    float* __restrict__ out, int b0) {
  const int x0 = blockIdx.x * 128;
  const int y0 = blockIdx.y * 8;
  const int bi = blockIdx.z;
  __shared__ __align__(16) float s_w3[1600][4];   // [c*25+ij][o] (o=3 +pad)
  __shared__ __align__(16) float s_in[4][12][136]; // 132 used
  const int tid = threadIdx.x;
  const int ry = tid >> 5;
  const int cx0 = (tid & 31) << 2;

  for (int idx = tid; idx < 1600; idx += 256)
    ((float4*)s_w3)[idx] = ((const float4*)w3t)[idx];

  float acc[3][4];
#pragma unroll
  for (int o = 0; o < 3; ++o)
#pragma unroll
    for (int p = 0; p < 4; ++p) acc[o][p] = 0.f;

  for (int cc = 0; cc < 16; ++cc) {
    __syncthreads();
    for (int idx = tid; idx < 4 * 12 * 132; idx += 256) {
      const int ci = idx / (12 * 132);
      const int r = (idx / 132) % 12;
      const int col = idx % 132;
      const int yy = y0 + r - 2;
      const int xx = x0 + col - 2;
      float v = 0.f;
      if (yy >= 0 && yy < HLAT && xx >= 0 && xx < WLON)
        v = h2[((size_t)(bi * 64 + cc * 4 + ci) * HLAT + yy) * WLON + xx];
      s_in[ci][r][col] = v;
    }
    __syncthreads();
#pragma unroll
    for (int ci = 0; ci < 4; ++ci) {
#pragma unroll
      for (int i = 0; i < 5; ++i) {
        const float4 a4 = *(const float4*)&s_in[ci][ry + i][cx0];
        const float4 b4 = *(const float4*)&s_in[ci][ry + i][cx0 + 4];
        const float win[8] = {a4.x, a4.y, a4.z, a4.w, b4.x, b4.y, b4.z, b4.w};
#pragma unroll
        for (int j = 0; j < 5; ++j) {
          const float4 w4 = *(const float4*)&s_w3[(cc * 4 + ci) * 25 + i * 5 + j][0];
          const float wv[3] = {w4.x, w4.y, w4.z};
#pragma unroll
          for (int p = 0; p < 4; ++p) {
            const float v = win[j + p];
#pragma unroll
            for (int o = 0; o < 3; ++o) acc[o][p] += wv[o] * v;
          }
        }
      }
    }
  }
  const int oy = y0 + ry;
  const int b = b0 + bi;
  if (oy < HLAT) {
#pragma unroll
    for (int o = 0; o < 3; ++o) {
      const float bb = b3[o];
      float* dst = out + ((size_t)(b * 3 + o) * HLAT + oy) * WLON;
#pragma unroll
      for (int p = 0; p < 4; ++p) {
        const int ox = x0 + cx0 + p;
        if (ox < WLON) dst[ox] = acc[o][p] + bb;
      }
    }
  }
}

extern "C" void kernel_launch(void* const* d_in, const int* in_sizes, int n_in,
                              void* d_out, int out_size, void* d_ws, size_t ws_size,
                              hipStream_t stream) {
  const float* x    = (const float*)d_in[0];
  const float* psi  = (const float*)d_in[1];
  const float* quad = (const float*)d_in[2];
  const float* w1   = (const float*)d_in[3];
  const float* b1   = (const float*)d_in[4];
  const float* w2   = (const float*)d_in[5];
  const float* b2   = (const float*)d_in[6];
  const float* w3   = (const float*)d_in[7];
  const float* b3   = (const float*)d_in[8];
  float* out = (float*)d_out;
  float* ws  = (float*)d_ws;

  float* w2t  = ws;            // 204800 floats
  float* w3t  = ws + 204800;   // 6400 floats
  float* pool = ws + 211200;

  size_t wsf = ws_size / 4;
  size_t avail = wsf > 211200 ? wsf - 211200 : 0;
  int bc = 8;  // batch chunk; shrink if workspace too small
  while (bc > 1 && (size_t)bc * 192 * HW > avail) bc >>= 1;

  k_tw<<<dim3(800), dim3(256), 0, stream>>>(w2, w3, w2t, w3t);

  float* h1 = pool;                               // bc*128*HW
  float* h2 = pool + (size_t)bc * 128 * HW;       // bc*64*HW
  for (int b0 = 0; b0 < 8; b0 += bc) {
    k_l1<<<dim3(HLAT, bc), dim3(192), 0, stream>>>(x, psi, quad, w1, b1, h1, b0);
    k_conv2<<<dim3(12, 46, bc), dim3(256), 0, stream>>>(h1, w2t, b2, h2);
    k_conv3<<<dim3(3, 23, bc), dim3(256), 0, stream>>>(h2, w3t, b3, out, b0);
  }
}

// Round 3
// 1524.091 us; speedup vs baseline: 3.6154x; 3.6154x over previous
//
#include <hip/hip_runtime.h>
#include <hip/hip_bf16.h>

#define HLAT 181
#define WLON 360
#define HW (HLAT * WLON)

typedef __attribute__((ext_vector_type(8)))  short short8v;
typedef __attribute__((ext_vector_type(16))) float f32x16;

static __device__ __forceinline__ ushort bf16_hi_bits(float f) {
  union { float f; unsigned u; } c; c.f = f;
  unsigned u = c.u;
  unsigned rounded = u + 0x7FFF + ((u >> 16) & 1);  // RNE
  return (ushort)(rounded >> 16);
}
static __device__ __forceinline__ float bf16_to_f(ushort b) {
  union { unsigned u; float f; } c; c.u = ((unsigned)b) << 16;
  return c.f;
}

// ---------------- kernel 0: weight prep ----------------
// w2f: ushort array, entry order ((((tap*8+ch)*2+m)*2+p)*64+l)*8+j
//   value = part{hi,lo} of w2[oc=m*32+(l&31)][ci=ch*16+(l>>5)*8+j][tap]
// w3t[c*25+ij][4] f32 (o=3 padded with 0)
__global__ __launch_bounds__(256) void k_tw(const float* __restrict__ w2,
                                            const float* __restrict__ w3,
                                            ushort* __restrict__ w2f,
                                            float* __restrict__ w3t) {
  int idx = blockIdx.x * 256 + threadIdx.x;
  if (idx < 51200) {
    int l   = idx & 63;
    int p   = (idx >> 6) & 1;
    int m   = (idx >> 7) & 1;
    int ch  = (idx >> 8) & 7;
    int tap = idx >> 11;
    int oc  = m * 32 + (l & 31);
    int ci0 = ch * 16 + (l >> 5) * 8;
#pragma unroll
    for (int j = 0; j < 8; ++j) {
      float f = w2[(oc * 128 + ci0 + j) * 25 + tap];
      ushort hi = bf16_hi_bits(f);
      ushort v;
      if (p == 0) v = hi;
      else        v = bf16_hi_bits(f - bf16_to_f(hi));
      w2f[(size_t)idx * 8 + j] = v;
    }
  }
  if (idx < 1600 * 4) {
    int ck = idx >> 2, o = idx & 3;
    int c = ck / 25, ij = ck % 25;
    w3t[idx] = (o < 3) ? w3[(o * 64 + c) * 25 + ij] : 0.f;
  }
}

// ---------------- kernel 1: disco conv + w1 GEMM + relu -> h1 px-major ---
// h1 layout: [bi][y][x][128ci] f32
__global__ __launch_bounds__(192) void k_l1(const float* __restrict__ x,
    const float* __restrict__ psi, const float* __restrict__ quad,
    const float* __restrict__ w1, const float* __restrict__ b1,
    float* __restrict__ h1, int b0) {
  const int h = blockIdx.x;
  const int bi = blockIdx.y;
  const int b = b0 + bi;
  __shared__ __align__(16) float s_w1[128][28]; // [o][c*9+k], col27 = 0
  __shared__ float s_psi[9][25];
  __shared__ float s_b1[128];
  const int tid = threadIdx.x;
  for (int idx = tid; idx < 128 * 27; idx += 192) s_w1[idx / 27][idx % 27] = w1[idx];
  for (int idx = tid; idx < 225; idx += 192)
    s_psi[idx / 25][idx % 25] = psi[(idx / 25) * (HLAT * 25) + h * 25 + (idx % 25)];
  if (tid < 128) { s_w1[tid][27] = 0.f; s_b1[tid] = b1[tid]; }
  __syncthreads();
  if (tid >= 180) return;

  float z[2][28];
#pragma unroll
  for (int q = 0; q < 28; ++q) { z[0][q] = 0.f; z[1][q] = 0.f; }

#pragma unroll
  for (int c = 0; c < 3; ++c) {
#pragma unroll
    for (int i = 0; i < 5; ++i) {
      int hi = h + i - 2;
      hi = hi < 0 ? 0 : (hi >= HLAT ? HLAT - 1 : hi);
      const float qv = quad[hi];
      const float* row = x + ((size_t)(b * 3 + c) * HLAT + hi) * WLON;
      float v0[5], v1[5];
#pragma unroll
      for (int j = 0; j < 5; ++j) {
        int wj0 = tid + j - 2; wj0 = wj0 < 0 ? wj0 + WLON : wj0;
        int wj1 = tid + 180 + j - 2; wj1 = wj1 >= WLON ? wj1 - WLON : wj1;
        v0[j] = row[wj0] * qv;
        v1[j] = row[wj1] * qv;
      }
#pragma unroll
      for (int k = 0; k < 9; ++k) {
        float a0 = 0.f, a1 = 0.f;
#pragma unroll
        for (int j = 0; j < 5; ++j) {
          const float p = s_psi[k][i * 5 + j];
          a0 += p * v0[j];
          a1 += p * v1[j];
        }
        z[0][c * 9 + k] += a0;
        z[1][c * 9 + k] += a1;
      }
    }
  }
  z[0][27] = 0.f; z[1][27] = 0.f;

  // h1 px-major: [bi][h][x][128]
  float* p0 = h1 + ((size_t)(bi * HLAT + h) * WLON + tid) * 128;
  float* p1 = h1 + ((size_t)(bi * HLAT + h) * WLON + tid + 180) * 128;
  float4 buf0, buf1;
  for (int o = 0; o < 128; ++o) {
    float a0 = s_b1[o], a1 = a0;
#pragma unroll
    for (int q4 = 0; q4 < 7; ++q4) {
      const float4 wv = *(const float4*)&s_w1[o][q4 * 4];
      a0 += wv.x * z[0][q4 * 4 + 0] + wv.y * z[0][q4 * 4 + 1] +
            wv.z * z[0][q4 * 4 + 2] + wv.w * z[0][q4 * 4 + 3];
      a1 += wv.x * z[1][q4 * 4 + 0] + wv.y * z[1][q4 * 4 + 1] +
            wv.z * z[1][q4 * 4 + 2] + wv.w * z[1][q4 * 4 + 3];
    }
    a0 = fmaxf(a0, 0.f); a1 = fmaxf(a1, 0.f);
    int r = o & 3;
    ((float*)&buf0)[r] = a0; ((float*)&buf1)[r] = a1;
    if (r == 3) {
      *(float4*)(p0 + (o - 3)) = buf0;
      *(float4*)(p1 + (o - 3)) = buf1;
    }
  }
}

// ---------------- kernel 2: conv 128->64 via bf16x3 MFMA ------------------
// grid (3, 46, bc) block 256 (4 waves). Out tile: 64oc x 4rows x 120cols.
// Wave = 1 row, 4 N-frags of 32 px (frag 3 partially masked: npx<120 owned).
// K loop: 8 ci-chunks of 16; per chunk per tap: mfma_f32_32x32x16_bf16.
__global__ __launch_bounds__(256, 2) void k_conv2(const float* __restrict__ h1,
    const ushort* __restrict__ w2f, const float* __restrict__ b2,
    float* __restrict__ h2) {
  __shared__ ushort act[2][8][128][16];  // [part][row][col][ci16] = 64 KB
  const int x0 = blockIdx.x * 120;
  const int y0 = blockIdx.y * 4;
  const int bi = blockIdx.z;
  const int tid = threadIdx.x;
  const int wv = tid >> 6;        // wave id = output row within tile
  const int l = tid & 63;
  const int l31 = l & 31;
  const int q = l >> 5;

  f32x16 acc[2][4];
#pragma unroll
  for (int m = 0; m < 2; ++m)
#pragma unroll
    for (int n = 0; n < 4; ++n)
#pragma unroll
      for (int r = 0; r < 16; ++r) acc[m][n][r] = 0.f;

  const float* h1b = h1 + (size_t)bi * HLAT * WLON * 128;
  const short8v* wf = (const short8v*)w2f;
  const short8v* actp = (const short8v*)&act[0][0][0][0];

  for (int ch = 0; ch < 8; ++ch) {
    __syncthreads();
    // ---- stage ci-chunk into LDS with hi/lo split (lane-linear writes) ----
    const int col_s = (l >> 1);          // 0..31 within col-group
    const int ci8 = (l & 1);             // which 8-ci half
#pragma unroll
    for (int s = 0; s < 8; ++s) {
      const int it = wv * 8 + s;         // 0..31
      const int row = it >> 2;           // 0..7
      const int col = (it & 3) * 32 + col_s;  // 0..127
      const int y = y0 - 2 + row;
      const int xx = x0 - 2 + col;
      float v[8];
      if (y >= 0 && y < HLAT && xx >= 0 && xx < WLON) {
        const float* src = h1b + ((size_t)y * WLON + xx) * 128 + ch * 16 + ci8 * 8;
        float4 fa = *(const float4*)src;
        float4 fb = *(const float4*)(src + 4);
        v[0]=fa.x; v[1]=fa.y; v[2]=fa.z; v[3]=fa.w;
        v[4]=fb.x; v[5]=fb.y; v[6]=fb.z; v[7]=fb.w;
      } else {
#pragma unroll
        for (int k = 0; k < 8; ++k) v[k] = 0.f;
      }
      union { ushort u[8]; short8v s8; } hi, lo;
#pragma unroll
      for (int k = 0; k < 8; ++k) {
        ushort hb = bf16_hi_bits(v[k]);
        hi.u[k] = hb;
        lo.u[k] = bf16_hi_bits(v[k] - bf16_to_f(hb));
      }
      ushort* dh = &act[0][row][col][ci8 * 8];
      ushort* dl = &act[1][row][col][ci8 * 8];
      *(short8v*)dh = hi.s8;
      *(short8v*)dl = lo.s8;
    }
    __syncthreads();
    // ---- compute: 25 taps ----
#pragma unroll 1
    for (int tap = 0; tap < 25; ++tap) {
      const int di = tap / 5, dj = tap % 5;
      const int e0 = ((tap * 8 + ch) * 2) * 2;  // entries of 64 short8
      short8v a0h = wf[(size_t)(e0 + 0) * 64 + l];
      short8v a0l = wf[(size_t)(e0 + 1) * 64 + l];
      short8v a1h = wf[(size_t)(e0 + 2) * 64 + l];
      short8v a1l = wf[(size_t)(e0 + 3) * 64 + l];
      const int row = wv + di;                  // 0..7
#pragma unroll
      for (int n = 0; n < 4; ++n) {
        int col = n * 32 + l31 + dj;            // >127 only for never-stored lanes
        col = col < 127 ? col : 127;            // keep LDS read in-bounds
        const int idxh = (row * 128 + col) * 2 + q;
        short8v bh = actp[idxh];
        short8v bl = actp[idxh + 2048];         // part stride = 32768B / 16
        acc[0][n] = __builtin_amdgcn_mfma_f32_32x32x16_bf16(a0h, bh, acc[0][n], 0, 0, 0);
        acc[0][n] = __builtin_amdgcn_mfma_f32_32x32x16_bf16(a0l, bh, acc[0][n], 0, 0, 0);
        acc[0][n] = __builtin_amdgcn_mfma_f32_32x32x16_bf16(a0h, bl, acc[0][n], 0, 0, 0);
        acc[1][n] = __builtin_amdgcn_mfma_f32_32x32x16_bf16(a1h, bh, acc[1][n], 0, 0, 0);
        acc[1][n] = __builtin_amdgcn_mfma_f32_32x32x16_bf16(a1l, bh, acc[1][n], 0, 0, 0);
        acc[1][n] = __builtin_amdgcn_mfma_f32_32x32x16_bf16(a1h, bl, acc[1][n], 0, 0, 0);
      }
    }
  }

  // ---- epilogue: bias + relu + store (strict tile ownership: npx < 120) ----
  const int y = y0 + wv;
  if (y < HLAT) {
#pragma unroll
    for (int m = 0; m < 2; ++m) {
#pragma unroll
      for (int r = 0; r < 16; ++r) {
        const int oc = m * 32 + (r & 3) + 8 * (r >> 2) + 4 * q;
        const float bb = b2[oc];
        float* dst = h2 + ((size_t)(bi * 64 + oc) * HLAT + y) * WLON;
#pragma unroll
        for (int n = 0; n < 4; ++n) {
          const int npx = n * 32 + l31;
          const int px = x0 + npx;
          if (npx < 120 && px < WLON)
            dst[px] = fmaxf(acc[m][n][r] + bb, 0.f);
        }
      }
    }
  }
}

// ---------------- kernel 3: conv 64->3, 5x5, zero pad (f32) ---------------
__global__ __launch_bounds__(256) void k_conv3(const float* __restrict__ h2,
    const float* __restrict__ w3t, const float* __restrict__ b3,
    float* __restrict__ out, int b0) {
  const int x0 = blockIdx.x * 128;
  const int y0 = blockIdx.y * 8;
  const int bi = blockIdx.z;
  __shared__ __align__(16) float s_w3[1600][4];
  __shared__ __align__(16) float s_in[4][12][136];
  const int tid = threadIdx.x;
  const int ry = tid >> 5;
  const int cx0 = (tid & 31) << 2;

  for (int idx = tid; idx < 1600; idx += 256)
    ((float4*)s_w3)[idx] = ((const float4*)w3t)[idx];

  float acc[3][4];
#pragma unroll
  for (int o = 0; o < 3; ++o)
#pragma unroll
    for (int p = 0; p < 4; ++p) acc[o][p] = 0.f;

  for (int cc = 0; cc < 16; ++cc) {
    __syncthreads();
    for (int idx = tid; idx < 4 * 12 * 132; idx += 256) {
      const int ci = idx / (12 * 132);
      const int r = (idx / 132) % 12;
      const int col = idx % 132;
      const int yy = y0 + r - 2;
      const int xx = x0 + col - 2;
      float v = 0.f;
      if (yy >= 0 && yy < HLAT && xx >= 0 && xx < WLON)
        v = h2[((size_t)(bi * 64 + cc * 4 + ci) * HLAT + yy) * WLON + xx];
      s_in[ci][r][col] = v;
    }
    __syncthreads();
#pragma unroll
    for (int ci = 0; ci < 4; ++ci) {
#pragma unroll
      for (int i = 0; i < 5; ++i) {
        const float4 a4 = *(const float4*)&s_in[ci][ry + i][cx0];
        const float4 b4 = *(const float4*)&s_in[ci][ry + i][cx0 + 4];
        const float win[8] = {a4.x, a4.y, a4.z, a4.w, b4.x, b4.y, b4.z, b4.w};
#pragma unroll
        for (int j = 0; j < 5; ++j) {
          const float4 w4 = *(const float4*)&s_w3[(cc * 4 + ci) * 25 + i * 5 + j][0];
          const float wv3[3] = {w4.x, w4.y, w4.z};
#pragma unroll
          for (int p = 0; p < 4; ++p) {
            const float v = win[j + p];
#pragma unroll
            for (int o = 0; o < 3; ++o) acc[o][p] += wv3[o] * v;
          }
        }
      }
    }
  }
  const int oy = y0 + ry;
  const int b = b0 + bi;
  if (oy < HLAT) {
#pragma unroll
    for (int o = 0; o < 3; ++o) {
      const float bb = b3[o];
      float* dst = out + ((size_t)(b * 3 + o) * HLAT + oy) * WLON;
#pragma unroll
      for (int p = 0; p < 4; ++p) {
        const int ox = x0 + cx0 + p;
        if (ox < WLON) dst[ox] = acc[o][p] + bb;
      }
    }
  }
}

extern "C" void kernel_launch(void* const* d_in, const int* in_sizes, int n_in,
                              void* d_out, int out_size, void* d_ws, size_t ws_size,
                              hipStream_t stream) {
  const float* x    = (const float*)d_in[0];
  const float* psi  = (const float*)d_in[1];
  const float* quad = (const float*)d_in[2];
  const float* w1   = (const float*)d_in[3];
  const float* b1   = (const float*)d_in[4];
  const float* w2   = (const float*)d_in[5];
  const float* b2   = (const float*)d_in[6];
  const float* w3   = (const float*)d_in[7];
  const float* b3   = (const float*)d_in[8];
  float* out = (float*)d_out;
  float* ws  = (float*)d_ws;

  float*  w3t = ws;                       // 6400 floats
  ushort* w2f = (ushort*)(ws + 6400);     // 409600 ushorts = 204800 float slots
  float*  pool = ws + 211200;

  size_t wsf = ws_size / 4;
  size_t avail = wsf > 211200 ? wsf - 211200 : 0;
  int bc = 4;
  while (bc > 1 && (size_t)bc * 192 * HW > avail) bc >>= 1;

  k_tw<<<dim3(200), dim3(256), 0, stream>>>(w2, w3, w2f, w3t);

  for (int b0 = 0; b0 < 8; b0 += bc) {
    int cur = 8 - b0 < bc ? 8 - b0 : bc;
    float* h1 = pool;                                  // cur*128*HW
    float* h2 = pool + (size_t)cur * 128 * HW;         // cur*64*HW
    k_l1<<<dim3(HLAT, cur), dim3(192), 0, stream>>>(x, psi, quad, w1, b1, h1, b0);
    k_conv2<<<dim3(3, 46, cur), dim3(256), 0, stream>>>(h1, w2f, b2, h2);
    k_conv3<<<dim3(3, 23, cur), dim3(256), 0, stream>>>(h2, w3t, b3, out, b0);
  }
}